// Round 2
// baseline (228.947 us; speedup 1.0000x reference)
//
#include <hip/hip_runtime.h>

// SSIM loss, fused: separable 11x11 Gaussian blur of 5 fields + ssim + mean.
// Round 2: no raw-tile LDS (hblur reads global directly), ds_write_b128 for
// hblur output, ds_read_b64 column-pair vblur, TH=32 halo amortization,
// atomic-ticket finalize (single kernel launch).

#define TW 64
#define TH 32
#define HALO 5
#define RH (TH + 2*HALO)   // 42 hblurred rows per tile
#define HS 68              // h row stride in words: 16B-aligned rows, bank-spread
#define NBLK 4096          // 8 x 16 x 32

typedef float f2 __attribute__((ext_vector_type(2)));
typedef float f4 __attribute__((ext_vector_type(4)));

__device__ __forceinline__ void hblur8_store(const float* __restrict__ W,
                                             const float (&x)[18],
                                             float* dst) {
    float s[8];
#pragma unroll
    for (int i = 0; i < 8; ++i) {
        float a = 0.f;
#pragma unroll
        for (int k = 0; k < 11; ++k) a = __builtin_fmaf(W[k], x[i + k], a);
        s[i] = a;
    }
    f4 lo, hi;
    lo.x = s[0]; lo.y = s[1]; lo.z = s[2]; lo.w = s[3];
    hi.x = s[4]; hi.y = s[5]; hi.z = s[6]; hi.w = s[7];
    *(f4*)dst = lo;
    *(f4*)(dst + 4) = hi;
}

__global__ __launch_bounds__(256, 2)
void ssim_main(const float* __restrict__ pred, const float* __restrict__ targ,
               float* __restrict__ acc, unsigned int* __restrict__ cnt,
               float* __restrict__ out) {
    const float W[11] = {
        0.00102840f, 0.00759876f, 0.03600077f, 0.10936070f, 0.21300554f,
        0.26601173f,
        0.21300554f, 0.10936070f, 0.03600077f, 0.00759876f, 0.00102840f};

    __shared__ float h[5][RH][HS];   // 57,120 B
    __shared__ float wsum[4];

    const int tid = threadIdx.x;
    const int n = blockIdx.z;
    const float* __restrict__ pim = pred + (size_t)n * (512 * 512);
    const float* __restrict__ tim = targ + (size_t)n * (512 * 512);
    const int tr0 = blockIdx.y * TH - HALO;
    const int tc0 = blockIdx.x * TW - HALO;
    const bool inner = (blockIdx.x > 0) & (blockIdx.x < 7) &
                       (blockIdx.y > 0) & (blockIdx.y < 15);

    // ---- Phase A: hblur 5 fields straight from global into LDS ----
    // 42 rows x 8 col-groups (8 outputs each) = 336 tasks
    for (int task = tid; task < RH * 8; task += 256) {
        const int r = task >> 3;
        const int cb8 = (task & 7) << 3;
        const int gr = tr0 + r;
        const int gc0 = tc0 + cb8;

        float p[18], t[18];
        if (inner) {
            const float* pr = pim + gr * 512 + gc0;
            const float* tr = tim + gr * 512 + gc0;
#pragma unroll
            for (int k = 0; k < 18; ++k) { p[k] = pr[k]; t[k] = tr[k]; }
        } else {
            const bool rok = (unsigned)gr < 512u;
            const int grc = min(max(gr, 0), 511);
            const float* pr = pim + grc * 512;
            const float* tr = tim + grc * 512;
#pragma unroll
            for (int k = 0; k < 18; ++k) {
                int gc = gc0 + k;
                bool ok = rok & ((unsigned)gc < 512u);
                int gcc = min(max(gc, 0), 511);
                float pv = pr[gcc], tv = tr[gcc];
                p[k] = ok ? pv : 0.f;
                t[k] = ok ? tv : 0.f;
            }
        }

        hblur8_store(W, p, &h[0][r][cb8]);
        hblur8_store(W, t, &h[1][r][cb8]);
        float q[18];
#pragma unroll
        for (int k = 0; k < 18; ++k) q[k] = p[k] * p[k];
        hblur8_store(W, q, &h[2][r][cb8]);
#pragma unroll
        for (int k = 0; k < 18; ++k) q[k] = t[k] * t[k];
        hblur8_store(W, q, &h[3][r][cb8]);
#pragma unroll
        for (int k = 0; k < 18; ++k) q[k] = p[k] * t[k];
        hblur8_store(W, q, &h[4][r][cb8]);
    }
    __syncthreads();

    // ---- Phase B: vblur via b64 column-pair reads + ssim ----
    // thread -> column pair (2 cols) x 4 output rows = 8 pixels
    const int cp2 = (tid & 31) * 2;
    const int r0 = (tid >> 5) * 4;

    f2 mu[5][4];
#pragma unroll
    for (int f = 0; f < 5; ++f) {
        f2 wv[14];
#pragma unroll
        for (int k = 0; k < 14; ++k)
            wv[k] = *(const f2*)&h[f][r0 + k][cp2];
#pragma unroll
        for (int i = 0; i < 4; ++i) {
            f2 s; s.x = 0.f; s.y = 0.f;
#pragma unroll
            for (int k = 0; k < 11; ++k) {
                s.x = __builtin_fmaf(W[k], wv[i + k].x, s.x);
                s.y = __builtin_fmaf(W[k], wv[i + k].y, s.y);
            }
            mu[f][i] = s;
        }
    }

    float lsum = 0.f;
#pragma unroll
    for (int i = 0; i < 4; ++i) {
#pragma unroll
        for (int c = 0; c < 2; ++c) {
            float m1 = mu[0][i][c], m2 = mu[1][i][c];
            float m1s = m1 * m1, m2s = m2 * m2, m12 = m1 * m2;
            float s1 = mu[2][i][c] - m1s;
            float s2 = mu[3][i][c] - m2s;
            float s12 = mu[4][i][c] - m12;
            float num = (2.f * m12 + 1e-4f) * (2.f * s12 + 9e-4f);
            float den = (m1s + m2s + 1e-4f) * (s1 + s2 + 9e-4f);
            float rc = __builtin_amdgcn_rcpf(den);
            rc = rc * (2.f - den * rc);
            lsum = __builtin_fmaf(num, rc, lsum);
        }
    }

    // ---- Reduce: wave shuffle -> block -> one atomic; ticket finalize ----
#pragma unroll
    for (int off = 32; off > 0; off >>= 1)
        lsum += __shfl_down(lsum, off, 64);
    if ((tid & 63) == 0) wsum[tid >> 6] = lsum;
    __syncthreads();
    if (tid == 0) {
        float b = wsum[0] + wsum[1] + wsum[2] + wsum[3];
        atomicAdd(acc, b);
        __threadfence();
        unsigned int old = atomicAdd(cnt, 1u);
        if (old == NBLK - 1) {
            float s = atomicAdd(acc, 0.f);   // coherent read of final sum
            out[0] = 1.0f - s * (1.0f / 8388608.0f);
        }
    }
}

extern "C" void kernel_launch(void* const* d_in, const int* in_sizes, int n_in,
                              void* d_out, int out_size, void* d_ws,
                              size_t ws_size, hipStream_t stream) {
    const float* pred = (const float*)d_in[0];
    const float* targ = (const float*)d_in[1];
    float* acc = (float*)d_ws;
    unsigned int* cnt = (unsigned int*)((char*)d_ws + 4);

    hipMemsetAsync(d_ws, 0, 8, stream);
    dim3 grid(512 / TW, 512 / TH, 32);  // 8 x 16 x 32 = 4096 blocks
    ssim_main<<<grid, dim3(256), 0, stream>>>(pred, targ, acc, cnt,
                                              (float*)d_out);
    (void)in_sizes; (void)n_in; (void)out_size; (void)ws_size;
}